// Round 9
// baseline (3007.466 us; speedup 1.0000x reference)
//
#include <hip/hip_runtime.h>
#include <math.h>
#include <cstdint>

#define BB 32
#define LL 256
#define TT 8192     // B*L
#define DIN 256
#define WEDm 200
#define PEDm 56
#define HH 512
#define G4 2048
#define MM 1024
#define EE 100
#define NTAGS 16

// ---------------- K1: embedding concat ----------------
__global__ void k_embed(const int* __restrict__ word, const int* __restrict__ posi,
                        const float* __restrict__ wemb, const float* __restrict__ pemb,
                        float* __restrict__ X) {
  int t = blockIdx.x;
  int c = threadIdx.x * 4;
  float4 v;
  if (c < WEDm) {
    int w = word[t];
    v = *(const float4*)(wemb + (size_t)w * WEDm + c);
  } else {
    int p = posi[t];
    v = *(const float4*)(pemb + (size_t)p * PEDm + (c - WEDm));
  }
  *(float4*)(X + (size_t)t * DIN + c) = v;
}

// ---------------- K2: fused dual GEMM  GX{f,b} = X @ Wx{f,b} + b{f,b} ----------------
__global__ __launch_bounds__(256) void k_gemm2(const float* __restrict__ X,
    const float* __restrict__ Wf, const float* __restrict__ Wb,
    const float* __restrict__ bf, const float* __restrict__ bb,
    float* __restrict__ GXf, float* __restrict__ GXb) {
  __shared__ float As[16][132];
  __shared__ float Bs[16][132];
  const int tid = threadIdx.x;
  const int row0 = blockIdx.y * 128;
  const int col0 = blockIdx.x * 128;     // 0..4095
  const int isB = (col0 >= G4) ? 1 : 0;
  const float* W = isB ? Wb : Wf;
  const float* bias = isB ? bb : bf;
  const int wcol0 = col0 - (isB ? G4 : 0);
  const int ar = tid >> 1, ac = (tid & 1) * 8;
  const int br = tid >> 4, bc = (tid & 15) * 8;
  const int ty = tid >> 4, tx = tid & 15;
  float acc[8][8] = {};
  for (int k0 = 0; k0 < DIN; k0 += 16) {
    float4 a0 = *(const float4*)(X + (size_t)(row0 + ar) * DIN + k0 + ac);
    float4 a1 = *(const float4*)(X + (size_t)(row0 + ar) * DIN + k0 + ac + 4);
    float4 b0 = *(const float4*)(W + (size_t)(k0 + br) * G4 + wcol0 + bc);
    float4 b1 = *(const float4*)(W + (size_t)(k0 + br) * G4 + wcol0 + bc + 4);
    As[ac + 0][ar] = a0.x; As[ac + 1][ar] = a0.y; As[ac + 2][ar] = a0.z; As[ac + 3][ar] = a0.w;
    As[ac + 4][ar] = a1.x; As[ac + 5][ar] = a1.y; As[ac + 6][ar] = a1.z; As[ac + 7][ar] = a1.w;
    *(float4*)(&Bs[br][bc]) = b0;
    *(float4*)(&Bs[br][bc + 4]) = b1;
    __syncthreads();
#pragma unroll
    for (int kk = 0; kk < 16; ++kk) {
      float4 aa0 = *(const float4*)(&As[kk][ty * 8]);
      float4 aa1 = *(const float4*)(&As[kk][ty * 8 + 4]);
      float4 bb0 = *(const float4*)(&Bs[kk][tx * 8]);
      float4 bb1 = *(const float4*)(&Bs[kk][tx * 8 + 4]);
      float a[8] = {aa0.x, aa0.y, aa0.z, aa0.w, aa1.x, aa1.y, aa1.z, aa1.w};
      float b[8] = {bb0.x, bb0.y, bb0.z, bb0.w, bb1.x, bb1.y, bb1.z, bb1.w};
#pragma unroll
      for (int i = 0; i < 8; ++i)
#pragma unroll
        for (int j = 0; j < 8; ++j)
          acc[i][j] += a[i] * b[j];
    }
    __syncthreads();
  }
  float* OUT = isB ? GXb : GXf;
#pragma unroll
  for (int i = 0; i < 8; ++i) {
    int row = row0 + ty * 8 + i;
#pragma unroll
    for (int j = 0; j < 8; ++j) {
      int col = wcol0 + tx * 8 + j;
      OUT[(size_t)row * G4 + col] = acc[i][j] + bias[col];
    }
  }
}

// ---------------- DPP helper: rotate-add within row16 ----------------
template <int N>
__device__ __forceinline__ float ror_add(float x) {
  int xi = __float_as_int(x);
  int yi = __builtin_amdgcn_update_dpp(xi, xi, 0x100 + N, 0xF, 0xF, false);
  return x + __int_as_float(yi);
}

__device__ __forceinline__ float sigm(float x) { return 1.f / (1.f + __expf(-x)); }

// ---------------- init Hpair slabs: slab0 = (h=0, seq=0); slab1 = invalid ----------------
__global__ void k_initH(unsigned long long* __restrict__ Hpair) {
  int i = blockIdx.x * 256 + threadIdx.x;           // 65536 total
  Hpair[i] = (i < 32768) ? 0ull : 0xFFFFFFFF00000000ull;
}

// ---------------- K3: LSTM, 512 WGs = dir(2) x bg(4x8batch) x ug(64x8unit) --------
// 256 thr/WG, wreg[4][4] (64 VGPR weights), launch_bounds(256,2) FORCES 2 waves/EU
// -> 2 WGs/CU co-resident by construction. Seq-tagged dataflow protocol.
__global__ __launch_bounds__(256, 2) void k_lstm9(
    const float* __restrict__ Whf, const float* __restrict__ Whb,
    const float* __restrict__ GXfp, const float* __restrict__ GXbp,
    const float* __restrict__ maskp, unsigned long long* __restrict__ Hpair,
    float* __restrict__ ctx) {
  extern __shared__ float lds[];
  float* Wtmp = lds;                // init only: [8 cols][512] (16KB)
  float* Hs   = lds;                // [8 b][516] overlays Wtmp after reg copy
  float* part = lds + 8 * 516;      // [2][32 lc][12]
  const int tid = threadIdx.x;
  const int wg  = blockIdx.x;
  const int dir = wg & 1;
  const int bg  = (wg >> 1) & 3;    // 4 batch groups x 8 batches
  const int ug  = wg >> 3;          // 64 unit groups x 8 units
  const int j0  = ug * 8;
  const int b0  = bg * 8;
  const float* Wh = dir ? Whb : Whf;
  const float* GX = dir ? GXbp : GXfp;

  const int ks = tid & 31;               // k lane: k = 4*ks + 128*j
  const int cq = tid >> 5;               // col chunk 0..7 (4 local cols each)
  const int uu = tid & 7, bloc = tid >> 3; // combine map (tid<64)

  // ---- stage Wh (32 cols x 512) into regs via 4 LDS chunks of 8 cols (gate q) ----
  // local col lc = q*8 + u; thread cq holds lc = cq*4 + ci (gate cq>>1, u (cq&1)*4+ci)
  float4 wreg[4][4];
#pragma unroll
  for (int cc = 0; cc < 4; ++cc) {
    for (int i = tid; i < 8 * 512; i += 256) {
      int c = i >> 9, k = i & 511;
      Wtmp[c * 512 + k] = Wh[(size_t)k * G4 + cc * HH + j0 + c];
    }
    __syncthreads();
    if ((cq >> 1) == cc) {
      int cbase = (cq & 1) * 4;
#pragma unroll
      for (int ci = 0; ci < 4; ++ci)
#pragma unroll
        for (int j = 0; j < 4; ++j)
          wreg[ci][j] = *(const float4*)(Wtmp + (cbase + ci) * 512 + 4 * ks + 128 * j);
    }
    __syncthreads();
  }

  float cstate = 0.f;

  for (int s = 0; s < LL; ++s) {
    const int t = dir ? (LL - 1 - s) : s;

    // ---- prefetch GX + mask (plain cached loads, independent of h) ----
    float gx0 = 0.f, gx1 = 0.f, gx2 = 0.f, gx3 = 0.f, mval = 0.f;
    if (tid < 64) {
      const float* gp = GX + ((size_t)((b0 + bloc) * LL + t)) * G4 + j0 + uu;
      gx0 = gp[0]; gx1 = gp[512]; gx2 = gp[1024]; gx3 = gp[1536];
      mval = maskp[(b0 + bloc) * LL + t];
    }

    // ---- consumer: seq-checked loads of h_s (slab s&1), 8 batches x 512 ----
    const unsigned long long* hb =
        Hpair + ((size_t)((s & 1) * 2 + dir) * 32 + b0) * 512;
    unsigned long long hv[16];
#pragma unroll
    for (int m = 0; m < 16; ++m)
      hv[m] = __hip_atomic_load(&hb[tid + 256 * m], __ATOMIC_RELAXED,
                                __HIP_MEMORY_SCOPE_AGENT);
    {
      const unsigned expect = (unsigned)s;
      int guard = 0;
      for (;;) {
        unsigned stale = 0u;
#pragma unroll
        for (int m = 0; m < 16; ++m)
          if ((unsigned)(hv[m] >> 32) != expect) stale |= (1u << m);
        if (!stale) break;
        if (++guard > (1 << 15)) break;   // hang guard
#pragma unroll
        for (int m = 0; m < 16; ++m)
          if (stale & (1u << m))
            hv[m] = __hip_atomic_load(&hb[tid + 256 * m], __ATOMIC_RELAXED,
                                      __HIP_MEMORY_SCOPE_AGENT);
      }
    }
#pragma unroll
    for (int m = 0; m < 16; ++m) {
      int f = tid + 256 * m;
      Hs[(f >> 9) * 516 + (f & 511)] = __uint_as_float((unsigned)hv[m]);
    }
    __syncthreads();

    // ---- 4x8 register-tiled matvec; Wh from regs, h from LDS ----
    float acc[4][8];
#pragma unroll
    for (int ci = 0; ci < 4; ++ci)
#pragma unroll
      for (int bi = 0; bi < 8; ++bi) acc[ci][bi] = 0.f;
    {
      const float* hp = Hs + 4 * ks;
#pragma unroll
      for (int j = 0; j < 4; ++j) {
        const int ko = 128 * j;
        float4 h4[8];
#pragma unroll
        for (int bi = 0; bi < 8; ++bi) h4[bi] = *(const float4*)(hp + bi * 516 + ko);
#pragma unroll
        for (int ci = 0; ci < 4; ++ci) {
          float4 w = wreg[ci][j];
#pragma unroll
          for (int bi = 0; bi < 8; ++bi) {
            float4 h = h4[bi];
            acc[ci][bi] += w.x * h.x + w.y * h.y + w.z * h.z + w.w * h.w;
          }
        }
      }
    }
    // ---- reduce over ks within row16 (ror-allreduce), 2 partial halves ----
#pragma unroll
    for (int ci = 0; ci < 4; ++ci)
#pragma unroll
      for (int bi = 0; bi < 8; ++bi) {
        float v = acc[ci][bi];
        v = ror_add<1>(v); v = ror_add<2>(v); v = ror_add<4>(v); v = ror_add<8>(v);
        acc[ci][bi] = v;
      }
    if ((ks & 15) == 0) {
      const int ph = ks >> 4;
      float* dst = part + ph * 384 + (cq * 4) * 12;
#pragma unroll
      for (int ci = 0; ci < 4; ++ci) {
        *(float4*)(dst + ci * 12 + 0) = make_float4(acc[ci][0], acc[ci][1], acc[ci][2], acc[ci][3]);
        *(float4*)(dst + ci * 12 + 4) = make_float4(acc[ci][4], acc[ci][5], acc[ci][6], acc[ci][7]);
      }
    }
    __syncthreads();

    // ---- gate combine (tid<64): unit uu (8), local batch bloc (8) ----
    if (tid < 64) {
      float pre[4];
#pragma unroll
      for (int q = 0; q < 4; ++q) {
        int lc = q * 8 + uu;
        pre[q] = part[lc * 12 + bloc] + part[384 + lc * 12 + bloc];
      }
      pre[0] += gx0; pre[1] += gx1; pre[2] += gx2; pre[3] += gx3;
      float gi = sigm(pre[0]);
      float gf = sigm(pre[1]);
      float gg = tanhf(pre[2]);
      float go = sigm(pre[3]);
      float cnew = gf * cstate + gi * gg;
      float hnew = go * tanhf(cnew);
      float hold = Hs[bloc * 516 + j0 + uu];
      float hn = hnew * mval + hold * (1.f - mval);
      cstate = cnew * mval + cstate * (1.f - mval);
      unsigned long long pk = ((unsigned long long)(unsigned)(s + 1) << 32) |
                              (unsigned long long)__float_as_uint(hn);
      __hip_atomic_store(
          &Hpair[((size_t)(((s + 1) & 1) * 2 + dir) * 32 + (b0 + bloc)) * 512 + j0 + uu],
          pk, __ATOMIC_RELAXED, __HIP_MEMORY_SCOPE_AGENT);
      ctx[((size_t)((b0 + bloc) * LL + t)) * (2 * HH) + dir * HH + j0 + uu] = hn;
    }
    __syncthreads();   // protect Hs/part before next-iter staging
  }
}

// ---------------- K4: tag histogram + stable compaction ----------------
__global__ void k_zero16(int* counts) { if (threadIdx.x < 16) counts[threadIdx.x] = 0; }

__global__ void k_count(const int* __restrict__ posi, int* __restrict__ counts) {
  int t = blockIdx.x * 256 + threadIdx.x;
  if (t < TT) atomicAdd(&counts[posi[t]], 1);
}

__global__ void k_prefix(const int* __restrict__ counts, int* __restrict__ offs) {
  if (threadIdx.x == 0) {
    int a = 0;
    for (int p = 0; p < NTAGS; ++p) { offs[p] = a; a += counts[p]; }
    offs[NTAGS] = a;
  }
}

__global__ __launch_bounds__(256) void k_compact(const int* __restrict__ posi,
    const int* __restrict__ offs, int* __restrict__ idxlist) {
  int p = blockIdx.x, tid = threadIdx.x;
  __shared__ int sc[256];
  __shared__ int sbase;
  if (tid == 0) sbase = offs[p];
  __syncthreads();
  for (int c0 = 0; c0 < TT; c0 += 256) {
    int t = c0 + tid;
    int f = (posi[t] == p) ? 1 : 0;
    int v = f;
    sc[tid] = v;
    __syncthreads();
    for (int o = 1; o < 256; o <<= 1) {
      int add = (tid >= o) ? sc[tid - o] : 0;
      __syncthreads();
      v += add;
      sc[tid] = v;
      __syncthreads();
    }
    int total = sc[255];
    int base = sbase;
    if (f) idxlist[base + v - 1] = t;
    __syncthreads();
    if (tid == 0) sbase = base + total;
    __syncthreads();
  }
}

// ---------------- K4b: gather per-tag psr rows ----------------
__global__ void k_ptbl(const int* __restrict__ wtbl, const float* __restrict__ psrw,
                       float* __restrict__ Ptbl) {
  int i = blockIdx.x * 256 + threadIdx.x;
  int total = NTAGS * MM * EE;
  for (; i < total; i += gridDim.x * 256) {
    int p = i / (MM * EE);
    int rem = i - p * (MM * EE);
    int r = rem / EE;
    int e = rem - r * EE;
    Ptbl[i] = psrw[(size_t)wtbl[p * MM + r] * EE + e];
  }
}

// ---------------- K5: grouped decoder GEMM, 128x128 tile / 8x8 micro ----------------
__global__ __launch_bounds__(256) void k_decgemm(const float* __restrict__ ctxb,
    const float* __restrict__ decW, const float* __restrict__ decb,
    const int* __restrict__ counts, const int* __restrict__ offs,
    const int* __restrict__ idxlist, float* __restrict__ Z) {
  int p = blockIdx.z;
  int n = counts[p];
  int r0 = blockIdx.y * 128;
  if (r0 >= n) return;
  int col0 = blockIdx.x * 128;
  __shared__ float As[16][132];
  __shared__ float Bs[16][132];
  __shared__ int rows[128];
  int tid = threadIdx.x;
  if (tid < 128) {
    int r = r0 + tid;
    rows[tid] = idxlist[offs[p] + (r < n ? r : n - 1)];
  }
  __syncthreads();
  const float* W = decW + (size_t)p * MM * MM;
  const int ar = tid >> 1, ac = (tid & 1) * 8;
  const int br = tid >> 4, bc = (tid & 15) * 8;
  const int ty = tid >> 4, tx = tid & 15;
  float acc[8][8] = {};
  for (int k0 = 0; k0 < MM; k0 += 16) {
    const float* ap = ctxb + (size_t)rows[ar] * MM + k0 + ac;
    float4 a0 = *(const float4*)(ap);
    float4 a1 = *(const float4*)(ap + 4);
    float4 b0 = *(const float4*)(W + (size_t)(k0 + br) * MM + col0 + bc);
    float4 b1 = *(const float4*)(W + (size_t)(k0 + br) * MM + col0 + bc + 4);
    As[ac + 0][ar] = a0.x; As[ac + 1][ar] = a0.y; As[ac + 2][ar] = a0.z; As[ac + 3][ar] = a0.w;
    As[ac + 4][ar] = a1.x; As[ac + 5][ar] = a1.y; As[ac + 6][ar] = a1.z; As[ac + 7][ar] = a1.w;
    *(float4*)(&Bs[br][bc]) = b0;
    *(float4*)(&Bs[br][bc + 4]) = b1;
    __syncthreads();
#pragma unroll
    for (int kk = 0; kk < 16; ++kk) {
      float4 aa0 = *(const float4*)(&As[kk][ty * 8]);
      float4 aa1 = *(const float4*)(&As[kk][ty * 8 + 4]);
      float4 bb0 = *(const float4*)(&Bs[kk][tx * 8]);
      float4 bb1 = *(const float4*)(&Bs[kk][tx * 8 + 4]);
      float a[8] = {aa0.x, aa0.y, aa0.z, aa0.w, aa1.x, aa1.y, aa1.z, aa1.w};
      float b[8] = {bb0.x, bb0.y, bb0.z, bb0.w, bb1.x, bb1.y, bb1.z, bb1.w};
#pragma unroll
      for (int i = 0; i < 8; ++i)
#pragma unroll
        for (int j = 0; j < 8; ++j)
          acc[i][j] += a[i] * b[j];
    }
    __syncthreads();
  }
#pragma unroll
  for (int i = 0; i < 8; ++i) {
    int r = ty * 8 + i;
    if (r0 + r < n) {
      int tok = rows[r];
#pragma unroll
      for (int j = 0; j < 8; ++j) {
        int col = col0 + tx * 8 + j;
        Z[(size_t)tok * MM + col] = acc[i][j] + decb[p * MM + col];
      }
    }
  }
}

// ---------------- K6: per-token softmax / entropy / gumbel argmax ----------------
__global__ __launch_bounds__(256) void k_softmax(
    const float* __restrict__ Z, const float* __restrict__ gum,
    const int* __restrict__ posi, const int* __restrict__ wflat,
    const int* __restrict__ wtbl, float* __restrict__ SPT,
    float* __restrict__ rowent, int* __restrict__ avoidb,
    float* __restrict__ out_word, float* __restrict__ out_mask,
    float* __restrict__ out_pri) {
  __shared__ float red[256];
  __shared__ float red2[256];
  __shared__ float redv[256];
  __shared__ int redi[256];
  int t = blockIdx.x, tid = threadIdx.x;
  float z[4];
#pragma unroll
  for (int i = 0; i < 4; ++i) z[i] = Z[(size_t)t * MM + tid + 256 * i];
  float mx = fmaxf(fmaxf(z[0], z[1]), fmaxf(z[2], z[3]));
  red[tid] = mx; __syncthreads();
  for (int o = 128; o > 0; o >>= 1) { if (tid < o) red[tid] = fmaxf(red[tid], red[tid + o]); __syncthreads(); }
  mx = red[0]; __syncthreads();
  float se = 0.f, we = 0.f;
#pragma unroll
  for (int i = 0; i < 4; ++i) {
    float d = z[i] - mx;
    float e = expf(d);
    se += e; we += d * e;
  }
  red[tid] = se; red2[tid] = we; __syncthreads();
  for (int o = 128; o > 0; o >>= 1) {
    if (tid < o) { red[tid] += red[tid + o]; red2[tid] += red2[tid + o]; }
    __syncthreads();
  }
  float se_tot = red[0], we_tot = red2[0]; __syncthreads();
  float lse = logf(se_tot);
  float ent = lse - we_tot / se_tot;
  float y[4];
#pragma unroll
  for (int i = 0; i < 4; ++i) {
    float u = gum[(size_t)t * MM + tid + 256 * i];
    float g = -logf(-logf(u + 1e-10f) + 1e-10f);
    y[i] = (z[i] - mx) + g;
  }
  float bv = y[0]; int bi = tid;
#pragma unroll
  for (int i = 1; i < 4; ++i) { int j = tid + 256 * i; if (y[i] > bv) { bv = y[i]; bi = j; } }
  redv[tid] = bv; redi[tid] = bi; __syncthreads();
  for (int o = 128; o > 0; o >>= 1) {
    if (tid < o) {
      float v2 = redv[tid + o]; int i2 = redi[tid + o];
      if (v2 > redv[tid] || (v2 == redv[tid] && i2 < redi[tid])) { redv[tid] = v2; redi[tid] = i2; }
    }
    __syncthreads();
  }
  float ymax = redv[0]; int amax = redi[0]; __syncthreads();
  float e2[4]; float s2 = 0.f;
#pragma unroll
  for (int i = 0; i < 4; ++i) { e2[i] = expf(y[i] - ymax); s2 += e2[i]; }
  red[tid] = s2; __syncthreads();
  for (int o = 128; o > 0; o >>= 1) { if (tid < o) red[tid] += red[tid + o]; __syncthreads(); }
  float inv = 1.f / red[0];
#pragma unroll
  for (int i = 0; i < 4; ++i) SPT[(size_t)t * MM + tid + 256 * i] = e2[i] * inv;
  if (tid == 0) {
    int p = posi[t];
    int widx = wtbl[p * MM + amax];
    int wf = wflat[t];
    int avoid = (widx == wf) ? 1 : 0;
    avoidb[t] = avoid;
    out_word[t] = (float)(avoid ? 0 : widx);
    out_mask[t] = 1.0f;
    out_pri[t] = (p < 4) ? 1.0f : 0.0f;
    rowent[t] = ent;
  }
}

// ---------------- K7: grouped emb GEMM ----------------
__global__ __launch_bounds__(256) void k_embgemm(const float* __restrict__ SPT,
    const float* __restrict__ Ptbl, const float* __restrict__ psrw,
    const int* __restrict__ counts, const int* __restrict__ offs,
    const int* __restrict__ idxlist, const int* __restrict__ avoidb,
    float* __restrict__ out_emb) {
  int p = blockIdx.y;
  int n = counts[p];
  int r0 = blockIdx.x * 64;
  if (r0 >= n) return;
  __shared__ float As[16][68];
  __shared__ float Bs[16][132];
  __shared__ int rows[64];
  int tid = threadIdx.x;
  if (tid < 64) rows[tid] = idxlist[offs[p] + ((r0 + tid) < n ? (r0 + tid) : 0)];
  __syncthreads();
  const float* P = Ptbl + (size_t)p * MM * EE;
  int tx = tid & 31, ty = tid >> 5;
  float acc[8][4] = {};
  for (int k0 = 0; k0 < MM; k0 += 16) {
    int r = tid >> 2, c = (tid & 3) * 4;
    float4 av = *(const float4*)(SPT + (size_t)rows[r] * MM + k0 + c);
    As[c + 0][r] = av.x; As[c + 1][r] = av.y; As[c + 2][r] = av.z; As[c + 3][r] = av.w;
    int r2 = tid >> 4;
    int c2 = (tid & 15) * 8;
    float4 b0 = make_float4(0.f, 0.f, 0.f, 0.f), b1 = make_float4(0.f, 0.f, 0.f, 0.f);
    if (c2 + 3 < EE) b0 = *(const float4*)(P + (size_t)(k0 + r2) * EE + c2);
    if (c2 + 7 < EE) b1 = *(const float4*)(P + (size_t)(k0 + r2) * EE + c2 + 4);
    *(float4*)(&Bs[r2][c2]) = b0;
    *(float4*)(&Bs[r2][c2 + 4]) = b1;
    __syncthreads();
#pragma unroll
    for (int kk = 0; kk < 16; ++kk) {
      float4 b4 = *(const float4*)(&Bs[kk][tx * 4]);
      float4 a0 = *(const float4*)(&As[kk][ty * 8]);
      float4 a1 = *(const float4*)(&As[kk][ty * 8 + 4]);
      float a[8] = {a0.x, a0.y, a0.z, a0.w, a1.x, a1.y, a1.z, a1.w};
#pragma unroll
      for (int ri = 0; ri < 8; ++ri) {
        acc[ri][0] += a[ri] * b4.x; acc[ri][1] += a[ri] * b4.y;
        acc[ri][2] += a[ri] * b4.z; acc[ri][3] += a[ri] * b4.w;
      }
    }
    __syncthreads();
  }
#pragma unroll
  for (int ri = 0; ri < 8; ++ri) {
    int r = ty * 8 + ri;
    if (r0 + r < n) {
      int tok = rows[r];
      int av = avoidb[tok];
#pragma unroll
      for (int j = 0; j < 4; ++j) {
        int col = tx * 4 + j;
        if (col < EE) {
          float v = av ? psrw[col] : acc[ri][j];
          out_emb[(size_t)tok * EE + col] = v;
        }
      }
    }
  }
}

// ---------------- K8: deterministic entropy-loss reduction ----------------
__global__ __launch_bounds__(256) void k_final(const float* __restrict__ rowent,
    const int* __restrict__ posi, const int* __restrict__ counts,
    float* __restrict__ out_loss) {
  __shared__ float red[256];
  int tid = threadIdx.x;
  float s = 0.f;
  for (int t = tid; t < TT; t += 256) {
    int p = posi[t];
    float denom = fmaxf((float)counts[p] * (float)MM, 1.0f);
    s += rowent[t] / denom;
  }
  red[tid] = s; __syncthreads();
  for (int o = 128; o > 0; o >>= 1) { if (tid < o) red[tid] += red[tid + o]; __syncthreads(); }
  if (tid == 0) out_loss[0] = -red[0] * 0.01f;
}

// ---------------- launcher ----------------
extern "C" void kernel_launch(void* const* d_in, const int* in_sizes, int n_in,
                              void* d_out, int out_size, void* d_ws, size_t ws_size,
                              hipStream_t stream) {
  const int*   inp_word = (const int*)d_in[0];
  const int*   inp_pos  = (const int*)d_in[1];
  const float* inp_mask = (const float*)d_in[2];
  const float* gum      = (const float*)d_in[3];
  const float* wemb     = (const float*)d_in[4];
  const float* pemb     = (const float*)d_in[5];
  const float* Wx_f     = (const float*)d_in[6];
  const float* Wh_f     = (const float*)d_in[7];
  const float* b_f      = (const float*)d_in[8];
  const float* Wx_b     = (const float*)d_in[9];
  const float* Wh_b     = (const float*)d_in[10];
  const float* b_b      = (const float*)d_in[11];
  const float* decW     = (const float*)d_in[12];
  const float* decb     = (const float*)d_in[13];
  const int*   wtbl     = (const int*)d_in[14];
  const float* psrw     = (const float*)d_in[15];

  float* out_word = (float*)d_out;
  float* out_emb  = out_word + TT;
  float* out_mask = out_emb + (size_t)TT * EE;
  float* out_pri  = out_mask + TT;
  float* out_loss = out_pri + TT;

  float* ws = (float*)d_ws;
  float* X      = ws;
  float* GXf    = X + (size_t)TT * DIN;
  float* GXb    = GXf + (size_t)TT * G4;
  float* ctxb   = GXb + (size_t)TT * G4;
  unsigned long long* Hpair = (unsigned long long*)(ctxb + (size_t)TT * MM);
  float* rowent = (float*)(Hpair + 65536);
  int* avoidb   = (int*)(rowent + TT);
  int* counts   = avoidb + TT;
  int* offs     = counts + 16;
  int* idxlist  = offs + 32;
  float* Z    = GXf;   // reuse: GX dead after LSTM
  float* SPT  = Z;     // in-place row rewrite in k_softmax
  float* Ptbl = GXb;   // reuse

  k_embed<<<TT, 64, 0, stream>>>(inp_word, inp_pos, wemb, pemb, X);
  k_gemm2<<<dim3(2 * G4 / 128, TT / 128), 256, 0, stream>>>(X, Wx_f, Wx_b, b_f, b_b, GXf, GXb);

  k_initH<<<256, 256, 0, stream>>>(Hpair);
  {
    const int ldsz = (8 * 516 + 2 * 32 * 12) * 4;  // 19584 B
    hipFuncSetAttribute((const void*)k_lstm9,
                        hipFuncAttributeMaxDynamicSharedMemorySize, ldsz);
    k_lstm9<<<512, 256, ldsz, stream>>>(Wh_f, Wh_b, GXf, GXb, inp_mask, Hpair, ctxb);
  }

  k_zero16<<<1, 64, 0, stream>>>(counts);
  k_count<<<TT / 256, 256, 0, stream>>>(inp_pos, counts);
  k_prefix<<<1, 64, 0, stream>>>(counts, offs);
  k_compact<<<NTAGS, 256, 0, stream>>>(inp_pos, offs, idxlist);
  k_ptbl<<<1024, 256, 0, stream>>>(wtbl, psrw, Ptbl);
  k_decgemm<<<dim3(MM / 128, TT / 128, NTAGS), 256, 0, stream>>>(ctxb, decW, decb, counts, offs, idxlist, Z);
  k_softmax<<<TT, 256, 0, stream>>>(Z, gum, inp_pos, inp_word, wtbl, SPT, rowent, avoidb,
                                    out_word, out_mask, out_pri);
  k_embgemm<<<dim3(TT / 64, NTAGS), 256, 0, stream>>>(SPT, Ptbl, psrw, counts, offs, idxlist,
                                                      avoidb, out_emb);
  k_final<<<1, 256, 0, stream>>>(rowent, inp_pos, counts, out_loss);
}

// Round 10
// 2160.762 us; speedup vs baseline: 1.3919x; 1.3919x over previous
//
#include <hip/hip_runtime.h>
#include <math.h>
#include <cstdint>

#define BB 32
#define LL 256
#define TT 8192     // B*L
#define DIN 256
#define WEDm 200
#define PEDm 56
#define HH 512
#define G4 2048
#define MM 1024
#define EE 100
#define NTAGS 16

// ---------------- K1: embedding concat ----------------
__global__ void k_embed(const int* __restrict__ word, const int* __restrict__ posi,
                        const float* __restrict__ wemb, const float* __restrict__ pemb,
                        float* __restrict__ X) {
  int t = blockIdx.x;
  int c = threadIdx.x * 4;
  float4 v;
  if (c < WEDm) {
    int w = word[t];
    v = *(const float4*)(wemb + (size_t)w * WEDm + c);
  } else {
    int p = posi[t];
    v = *(const float4*)(pemb + (size_t)p * PEDm + (c - WEDm));
  }
  *(float4*)(X + (size_t)t * DIN + c) = v;
}

// ---------------- K2: fused dual GEMM  GX{f,b} = X @ Wx{f,b} + b{f,b} ----------------
__global__ __launch_bounds__(256) void k_gemm2(const float* __restrict__ X,
    const float* __restrict__ Wf, const float* __restrict__ Wb,
    const float* __restrict__ bf, const float* __restrict__ bb,
    float* __restrict__ GXf, float* __restrict__ GXb) {
  __shared__ float As[16][132];
  __shared__ float Bs[16][132];
  const int tid = threadIdx.x;
  const int row0 = blockIdx.y * 128;
  const int col0 = blockIdx.x * 128;     // 0..4095
  const int isB = (col0 >= G4) ? 1 : 0;
  const float* W = isB ? Wb : Wf;
  const float* bias = isB ? bb : bf;
  const int wcol0 = col0 - (isB ? G4 : 0);
  const int ar = tid >> 1, ac = (tid & 1) * 8;
  const int br = tid >> 4, bc = (tid & 15) * 8;
  const int ty = tid >> 4, tx = tid & 15;
  float acc[8][8] = {};
  for (int k0 = 0; k0 < DIN; k0 += 16) {
    float4 a0 = *(const float4*)(X + (size_t)(row0 + ar) * DIN + k0 + ac);
    float4 a1 = *(const float4*)(X + (size_t)(row0 + ar) * DIN + k0 + ac + 4);
    float4 b0 = *(const float4*)(W + (size_t)(k0 + br) * G4 + wcol0 + bc);
    float4 b1 = *(const float4*)(W + (size_t)(k0 + br) * G4 + wcol0 + bc + 4);
    As[ac + 0][ar] = a0.x; As[ac + 1][ar] = a0.y; As[ac + 2][ar] = a0.z; As[ac + 3][ar] = a0.w;
    As[ac + 4][ar] = a1.x; As[ac + 5][ar] = a1.y; As[ac + 6][ar] = a1.z; As[ac + 7][ar] = a1.w;
    *(float4*)(&Bs[br][bc]) = b0;
    *(float4*)(&Bs[br][bc + 4]) = b1;
    __syncthreads();
#pragma unroll
    for (int kk = 0; kk < 16; ++kk) {
      float4 aa0 = *(const float4*)(&As[kk][ty * 8]);
      float4 aa1 = *(const float4*)(&As[kk][ty * 8 + 4]);
      float4 bb0 = *(const float4*)(&Bs[kk][tx * 8]);
      float4 bb1 = *(const float4*)(&Bs[kk][tx * 8 + 4]);
      float a[8] = {aa0.x, aa0.y, aa0.z, aa0.w, aa1.x, aa1.y, aa1.z, aa1.w};
      float b[8] = {bb0.x, bb0.y, bb0.z, bb0.w, bb1.x, bb1.y, bb1.z, bb1.w};
#pragma unroll
      for (int i = 0; i < 8; ++i)
#pragma unroll
        for (int j = 0; j < 8; ++j)
          acc[i][j] += a[i] * b[j];
    }
    __syncthreads();
  }
  float* OUT = isB ? GXb : GXf;
#pragma unroll
  for (int i = 0; i < 8; ++i) {
    int row = row0 + ty * 8 + i;
#pragma unroll
    for (int j = 0; j < 8; ++j) {
      int col = wcol0 + tx * 8 + j;
      OUT[(size_t)row * G4 + col] = acc[i][j] + bias[col];
    }
  }
}

// ---------------- DPP helper: rotate-add within row16 ----------------
template <int N>
__device__ __forceinline__ float ror_add(float x) {
  int xi = __float_as_int(x);
  int yi = __builtin_amdgcn_update_dpp(xi, xi, 0x100 + N, 0xF, 0xF, false);
  return x + __int_as_float(yi);
}

__device__ __forceinline__ float sigm(float x) { return 1.f / (1.f + __expf(-x)); }

// ---------------- init Hpair slabs: slab0 = (h=0, seq=0); slab1 = invalid ----------------
__global__ void k_initH(unsigned long long* __restrict__ Hpair) {
  int i = blockIdx.x * 256 + threadIdx.x;           // 65536 total
  Hpair[i] = (i < 32768) ? 0ull : 0xFFFFFFFF00000000ull;
}

// ---------------- K3: LSTM, 256 WGs = dir(2) x bgroup(4x8b) x ugroup(32x16u) ----------
// Seq-tagged dataflow: each h word is (seq<<32)|f32bits, stored/loaded with 8B
// relaxed agent atomics. Consumers poll data words directly (per-word seq check,
// masked retry) -- no flags, no vmcnt drain on the producer side. 2-slab parity.
// (VERBATIM round-7 kernel -- proven 1.41 ms / absmax clean.)
__global__ __launch_bounds__(512, 1) void k_lstm7(
    const float* __restrict__ Whf, const float* __restrict__ Whb,
    const float* __restrict__ GXfp, const float* __restrict__ GXbp,
    const float* __restrict__ maskp, unsigned long long* __restrict__ Hpair,
    float* __restrict__ ctx) {
  extern __shared__ float lds[];
  float* Wtmp = lds;                // init only: [16 cols][512] (32KB)
  float* Hs   = lds;                // [8 b][516] overlays Wtmp after reg copy
  float* part = lds + 8 * 516;      // [2][64 lc][12]
  const int tid = threadIdx.x;
  const int wg  = blockIdx.x;
  const int dir = wg & 1;
  const int bg  = (wg >> 1) & 3;    // batch group: 8 batches
  const int ug  = wg >> 3;          // unit group 0..31: 16 units
  const int j0  = ug * 16;
  const int b0  = bg * 8;
  const float* Wh = dir ? Whb : Whf;
  const float* GX = dir ? GXbp : GXfp;

  const int ks = tid & 31;               // k lane: k = 4*ks + 128*j
  const int cq = tid >> 5;               // col group 0..15 (4 local cols each)
  const int uu = tid & 15, bloc = tid >> 4; // combine map (tid<128)

  // ---- stage Wh (64 cols x 512) into regs via 4 LDS chunks of 16 cols ----
  float4 wreg[4][4];
#pragma unroll
  for (int cc = 0; cc < 4; ++cc) {
    for (int i = tid; i < 16 * 512; i += 512) {
      int c = i >> 9, k = i & 511;
      Wtmp[c * 512 + k] = Wh[(size_t)k * G4 + cc * HH + j0 + c];
    }
    __syncthreads();
    if ((cq >> 2) == cc) {
      int cbase = (cq & 3) * 4;
#pragma unroll
      for (int ci = 0; ci < 4; ++ci)
#pragma unroll
        for (int j = 0; j < 4; ++j)
          wreg[ci][j] = *(const float4*)(Wtmp + (cbase + ci) * 512 + 4 * ks + 128 * j);
    }
    __syncthreads();
  }

  float cstate = 0.f;

  for (int s = 0; s < LL; ++s) {
    const int t = dir ? (LL - 1 - s) : s;

    // ---- prefetch GX + mask (plain cached loads, independent of h) ----
    float gx0 = 0.f, gx1 = 0.f, gx2 = 0.f, gx3 = 0.f, mval = 0.f;
    if (tid < 128) {
      const float* gp = GX + ((size_t)((b0 + bloc) * LL + t)) * G4 + j0 + uu;
      gx0 = gp[0]; gx1 = gp[512]; gx2 = gp[1024]; gx3 = gp[1536];
      mval = maskp[(b0 + bloc) * LL + t];
    }

    // ---- consumer: seq-checked pair loads of h_s (slab s&1) ----
    const unsigned long long* hb =
        Hpair + ((size_t)((s & 1) * 2 + dir) * 32 + b0) * 512;
    unsigned long long hv[8];
#pragma unroll
    for (int m = 0; m < 8; ++m)
      hv[m] = __hip_atomic_load(&hb[tid + 512 * m], __ATOMIC_RELAXED,
                                __HIP_MEMORY_SCOPE_AGENT);
    {
      const unsigned expect = (unsigned)s;
      int guard = 0;
      for (;;) {
        unsigned stale = 0u;
#pragma unroll
        for (int m = 0; m < 8; ++m)
          if ((unsigned)(hv[m] >> 32) != expect) stale |= (1u << m);
        if (!stale) break;
        if (++guard > (1 << 15)) break;   // hang guard
#pragma unroll
        for (int m = 0; m < 8; ++m)
          if (stale & (1u << m))
            hv[m] = __hip_atomic_load(&hb[tid + 512 * m], __ATOMIC_RELAXED,
                                      __HIP_MEMORY_SCOPE_AGENT);
      }
    }
#pragma unroll
    for (int m = 0; m < 8; ++m) {
      int f = tid + 512 * m;
      Hs[(f >> 9) * 516 + (f & 511)] = __uint_as_float((unsigned)hv[m]);
    }
    __syncthreads();

    // ---- 4x8 register-tiled matvec; Wh from regs, h from LDS ----
    float acc[4][8];
#pragma unroll
    for (int ci = 0; ci < 4; ++ci)
#pragma unroll
      for (int bi = 0; bi < 8; ++bi) acc[ci][bi] = 0.f;
    {
      const float* hp = Hs + 4 * ks;
#pragma unroll
      for (int j = 0; j < 4; ++j) {
        const int ko = 128 * j;
        float4 h4[8];
#pragma unroll
        for (int bi = 0; bi < 8; ++bi) h4[bi] = *(const float4*)(hp + bi * 516 + ko);
#pragma unroll
        for (int ci = 0; ci < 4; ++ci) {
          float4 w = wreg[ci][j];
#pragma unroll
          for (int bi = 0; bi < 8; ++bi) {
            float4 h = h4[bi];
            acc[ci][bi] += w.x * h.x + w.y * h.y + w.z * h.z + w.w * h.w;
          }
        }
      }
    }
    // ---- reduce over ks within row16 (ror-allreduce), 2 partials ----
#pragma unroll
    for (int ci = 0; ci < 4; ++ci)
#pragma unroll
      for (int bi = 0; bi < 8; ++bi) {
        float v = acc[ci][bi];
        v = ror_add<1>(v); v = ror_add<2>(v); v = ror_add<4>(v); v = ror_add<8>(v);
        acc[ci][bi] = v;
      }
    if ((ks & 15) == 0) {
      const int ph = ks >> 4;
      float* dst = part + ph * 768 + (cq * 4) * 12;
#pragma unroll
      for (int ci = 0; ci < 4; ++ci) {
        *(float4*)(dst + ci * 12 + 0) = make_float4(acc[ci][0], acc[ci][1], acc[ci][2], acc[ci][3]);
        *(float4*)(dst + ci * 12 + 4) = make_float4(acc[ci][4], acc[ci][5], acc[ci][6], acc[ci][7]);
      }
    }
    __syncthreads();

    // ---- gate combine (tid<128) + producer store (h_{s+1}, seq s+1) ----
    if (tid < 128) {
      float pre[4];
#pragma unroll
      for (int q = 0; q < 4; ++q) {
        int lc = q * 16 + uu;
        pre[q] = part[lc * 12 + bloc] + part[768 + lc * 12 + bloc];
      }
      pre[0] += gx0; pre[1] += gx1; pre[2] += gx2; pre[3] += gx3;
      float gi = sigm(pre[0]);
      float gf = sigm(pre[1]);
      float gg = tanhf(pre[2]);
      float go = sigm(pre[3]);
      float cnew = gf * cstate + gi * gg;
      float hnew = go * tanhf(cnew);
      float hold = Hs[bloc * 516 + j0 + uu];
      float hn = hnew * mval + hold * (1.f - mval);
      cstate = cnew * mval + cstate * (1.f - mval);
      unsigned long long pk = ((unsigned long long)(unsigned)(s + 1) << 32) |
                              (unsigned long long)__float_as_uint(hn);
      __hip_atomic_store(
          &Hpair[((size_t)(((s + 1) & 1) * 2 + dir) * 32 + (b0 + bloc)) * 512 + j0 + uu],
          pk, __ATOMIC_RELAXED, __HIP_MEMORY_SCOPE_AGENT);
      ctx[((size_t)((b0 + bloc) * LL + t)) * (2 * HH) + dir * HH + j0 + uu] = hn;
    }
    __syncthreads();   // protect Hs/part before next-iter staging
  }
}

// ---------------- K4: tag histogram + stable compaction (ballot-based) ----------------
__global__ void k_zero16(int* counts) { if (threadIdx.x < 16) counts[threadIdx.x] = 0; }

__global__ void k_count(const int* __restrict__ posi, int* __restrict__ counts) {
  int t = blockIdx.x * 256 + threadIdx.x;
  if (t < TT) atomicAdd(&counts[posi[t]], 1);
}

__global__ void k_prefix(const int* __restrict__ counts, int* __restrict__ offs) {
  if (threadIdx.x == 0) {
    int a = 0;
    for (int p = 0; p < NTAGS; ++p) { offs[p] = a; a += counts[p]; }
    offs[NTAGS] = a;
  }
}

__global__ __launch_bounds__(256) void k_compact(const int* __restrict__ posi,
    const int* __restrict__ offs, int* __restrict__ idxlist) {
  int p = blockIdx.x, tid = threadIdx.x;
  int lane = tid & 63, wid = tid >> 6;
  __shared__ int wsum[4];
  __shared__ int sbase;
  if (tid == 0) sbase = offs[p];
  __syncthreads();
  for (int c0 = 0; c0 < TT; c0 += 256) {
    int t = c0 + tid;
    bool f = (posi[t] == p);
    unsigned long long m = __ballot(f);
    int lpfx = __popcll(m & ((1ull << lane) - 1ull));
    if (lane == 0) wsum[wid] = __popcll(m);
    __syncthreads();
    int wpfx = 0;
#pragma unroll
    for (int w = 0; w < 4; ++w) wpfx += (w < wid) ? wsum[w] : 0;
    int total = wsum[0] + wsum[1] + wsum[2] + wsum[3];
    if (f) idxlist[sbase + wpfx + lpfx] = t;
    __syncthreads();
    if (tid == 0) sbase += total;
    __syncthreads();
  }
}

// ---------------- K5: grouped decoder GEMM, 128x128 tile / 8x8 micro ----------------
__global__ __launch_bounds__(256) void k_decgemm(const float* __restrict__ ctxb,
    const float* __restrict__ decW, const float* __restrict__ decb,
    const int* __restrict__ counts, const int* __restrict__ offs,
    const int* __restrict__ idxlist, float* __restrict__ Z) {
  int p = blockIdx.z;
  int n = counts[p];
  int r0 = blockIdx.y * 128;
  if (r0 >= n) return;
  int col0 = blockIdx.x * 128;
  __shared__ float As[16][132];
  __shared__ float Bs[16][132];
  __shared__ int rows[128];
  int tid = threadIdx.x;
  if (tid < 128) {
    int r = r0 + tid;
    rows[tid] = idxlist[offs[p] + (r < n ? r : n - 1)];
  }
  __syncthreads();
  const float* W = decW + (size_t)p * MM * MM;
  const int ar = tid >> 1, ac = (tid & 1) * 8;
  const int br = tid >> 4, bc = (tid & 15) * 8;
  const int ty = tid >> 4, tx = tid & 15;
  float acc[8][8] = {};
  for (int k0 = 0; k0 < MM; k0 += 16) {
    const float* ap = ctxb + (size_t)rows[ar] * MM + k0 + ac;
    float4 a0 = *(const float4*)(ap);
    float4 a1 = *(const float4*)(ap + 4);
    float4 b0 = *(const float4*)(W + (size_t)(k0 + br) * MM + col0 + bc);
    float4 b1 = *(const float4*)(W + (size_t)(k0 + br) * MM + col0 + bc + 4);
    As[ac + 0][ar] = a0.x; As[ac + 1][ar] = a0.y; As[ac + 2][ar] = a0.z; As[ac + 3][ar] = a0.w;
    As[ac + 4][ar] = a1.x; As[ac + 5][ar] = a1.y; As[ac + 6][ar] = a1.z; As[ac + 7][ar] = a1.w;
    *(float4*)(&Bs[br][bc]) = b0;
    *(float4*)(&Bs[br][bc + 4]) = b1;
    __syncthreads();
#pragma unroll
    for (int kk = 0; kk < 16; ++kk) {
      float4 aa0 = *(const float4*)(&As[kk][ty * 8]);
      float4 aa1 = *(const float4*)(&As[kk][ty * 8 + 4]);
      float4 bb0 = *(const float4*)(&Bs[kk][tx * 8]);
      float4 bb1 = *(const float4*)(&Bs[kk][tx * 8 + 4]);
      float a[8] = {aa0.x, aa0.y, aa0.z, aa0.w, aa1.x, aa1.y, aa1.z, aa1.w};
      float b[8] = {bb0.x, bb0.y, bb0.z, bb0.w, bb1.x, bb1.y, bb1.z, bb1.w};
#pragma unroll
      for (int i = 0; i < 8; ++i)
#pragma unroll
        for (int j = 0; j < 8; ++j)
          acc[i][j] += a[i] * b[j];
    }
    __syncthreads();
  }
#pragma unroll
  for (int i = 0; i < 8; ++i) {
    int r = ty * 8 + i;
    if (r0 + r < n) {
      int tok = rows[r];
#pragma unroll
      for (int j = 0; j < 8; ++j) {
        int col = col0 + tx * 8 + j;
        Z[(size_t)tok * MM + col] = acc[i][j] + decb[p * MM + col];
      }
    }
  }
}

// ---------------- K6: per-token softmax / entropy / gumbel argmax ----------------
__global__ __launch_bounds__(256) void k_softmax(
    const float* __restrict__ Z, const float* __restrict__ gum,
    const int* __restrict__ posi, const int* __restrict__ wflat,
    const int* __restrict__ wtbl, float* __restrict__ SPT,
    float* __restrict__ rowent, int* __restrict__ avoidb,
    float* __restrict__ out_word, float* __restrict__ out_mask,
    float* __restrict__ out_pri) {
  __shared__ float red[256];
  __shared__ float red2[256];
  __shared__ float redv[256];
  __shared__ int redi[256];
  int t = blockIdx.x, tid = threadIdx.x;
  float z[4];
#pragma unroll
  for (int i = 0; i < 4; ++i) z[i] = Z[(size_t)t * MM + tid + 256 * i];
  float mx = fmaxf(fmaxf(z[0], z[1]), fmaxf(z[2], z[3]));
  red[tid] = mx; __syncthreads();
  for (int o = 128; o > 0; o >>= 1) { if (tid < o) red[tid] = fmaxf(red[tid], red[tid + o]); __syncthreads(); }
  mx = red[0]; __syncthreads();
  float se = 0.f, we = 0.f;
#pragma unroll
  for (int i = 0; i < 4; ++i) {
    float d = z[i] - mx;
    float e = expf(d);
    se += e; we += d * e;
  }
  red[tid] = se; red2[tid] = we; __syncthreads();
  for (int o = 128; o > 0; o >>= 1) {
    if (tid < o) { red[tid] += red[tid + o]; red2[tid] += red2[tid + o]; }
    __syncthreads();
  }
  float se_tot = red[0], we_tot = red2[0]; __syncthreads();
  float lse = logf(se_tot);
  float ent = lse - we_tot / se_tot;
  float y[4];
#pragma unroll
  for (int i = 0; i < 4; ++i) {
    float u = gum[(size_t)t * MM + tid + 256 * i];
    float g = -logf(-logf(u + 1e-10f) + 1e-10f);
    y[i] = (z[i] - mx) + g;
  }
  float bv = y[0]; int bi = tid;
#pragma unroll
  for (int i = 1; i < 4; ++i) { int j = tid + 256 * i; if (y[i] > bv) { bv = y[i]; bi = j; } }
  redv[tid] = bv; redi[tid] = bi; __syncthreads();
  for (int o = 128; o > 0; o >>= 1) {
    if (tid < o) {
      float v2 = redv[tid + o]; int i2 = redi[tid + o];
      if (v2 > redv[tid] || (v2 == redv[tid] && i2 < redi[tid])) { redv[tid] = v2; redi[tid] = i2; }
    }
    __syncthreads();
  }
  float ymax = redv[0]; int amax = redi[0]; __syncthreads();
  float e2[4]; float s2 = 0.f;
#pragma unroll
  for (int i = 0; i < 4; ++i) { e2[i] = expf(y[i] - ymax); s2 += e2[i]; }
  red[tid] = s2; __syncthreads();
  for (int o = 128; o > 0; o >>= 1) { if (tid < o) red[tid] += red[tid + o]; __syncthreads(); }
  float inv = 1.f / red[0];
#pragma unroll
  for (int i = 0; i < 4; ++i) SPT[(size_t)t * MM + tid + 256 * i] = e2[i] * inv;
  if (tid == 0) {
    int p = posi[t];
    int widx = wtbl[p * MM + amax];
    int wf = wflat[t];
    int avoid = (widx == wf) ? 1 : 0;
    avoidb[t] = avoid;
    out_word[t] = (float)(avoid ? 0 : widx);
    out_mask[t] = 1.0f;
    out_pri[t] = (p < 4) ? 1.0f : 0.0f;
    rowent[t] = ent;
  }
}

// ---------------- K7: grouped emb GEMM (psr rows gathered via wtbl, no Ptbl) --------
__global__ __launch_bounds__(256) void k_embgemm(const float* __restrict__ SPT,
    const int* __restrict__ wtbl, const float* __restrict__ psrw,
    const int* __restrict__ counts, const int* __restrict__ offs,
    const int* __restrict__ idxlist, const int* __restrict__ avoidb,
    float* __restrict__ out_emb) {
  int p = blockIdx.y;
  int n = counts[p];
  int r0 = blockIdx.x * 64;
  if (r0 >= n) return;
  __shared__ float As[16][68];
  __shared__ float Bs[16][132];
  __shared__ int rows[64];
  int tid = threadIdx.x;
  if (tid < 64) rows[tid] = idxlist[offs[p] + ((r0 + tid) < n ? (r0 + tid) : 0)];
  __syncthreads();
  int tx = tid & 31, ty = tid >> 5;
  float acc[8][4] = {};
  for (int k0 = 0; k0 < MM; k0 += 16) {
    int r = tid >> 2, c = (tid & 3) * 4;
    float4 av = *(const float4*)(SPT + (size_t)rows[r] * MM + k0 + c);
    As[c + 0][r] = av.x; As[c + 1][r] = av.y; As[c + 2][r] = av.z; As[c + 3][r] = av.w;
    int r2 = tid >> 4;
    int c2 = (tid & 15) * 8;
    int widx = wtbl[p * MM + k0 + r2];
    const float* prow = psrw + (size_t)widx * EE;
    float4 b0 = make_float4(0.f, 0.f, 0.f, 0.f), b1 = make_float4(0.f, 0.f, 0.f, 0.f);
    if (c2 + 3 < EE) b0 = *(const float4*)(prow + c2);
    if (c2 + 7 < EE) b1 = *(const float4*)(prow + c2 + 4);
    *(float4*)(&Bs[r2][c2]) = b0;
    *(float4*)(&Bs[r2][c2 + 4]) = b1;
    __syncthreads();
#pragma unroll
    for (int kk = 0; kk < 16; ++kk) {
      float4 b4 = *(const float4*)(&Bs[kk][tx * 4]);
      float4 a0 = *(const float4*)(&As[kk][ty * 8]);
      float4 a1 = *(const float4*)(&As[kk][ty * 8 + 4]);
      float a[8] = {a0.x, a0.y, a0.z, a0.w, a1.x, a1.y, a1.z, a1.w};
#pragma unroll
      for (int ri = 0; ri < 8; ++ri) {
        acc[ri][0] += a[ri] * b4.x; acc[ri][1] += a[ri] * b4.y;
        acc[ri][2] += a[ri] * b4.z; acc[ri][3] += a[ri] * b4.w;
      }
    }
    __syncthreads();
  }
#pragma unroll
  for (int ri = 0; ri < 8; ++ri) {
    int r = ty * 8 + ri;
    if (r0 + r < n) {
      int tok = rows[r];
      int av = avoidb[tok];
#pragma unroll
      for (int j = 0; j < 4; ++j) {
        int col = tx * 4 + j;
        if (col < EE) {
          float v = av ? psrw[col] : acc[ri][j];
          out_emb[(size_t)tok * EE + col] = v;
        }
      }
    }
  }
}

// ---------------- K8: deterministic entropy-loss reduction ----------------
__global__ __launch_bounds__(256) void k_final(const float* __restrict__ rowent,
    const int* __restrict__ posi, const int* __restrict__ counts,
    float* __restrict__ out_loss) {
  __shared__ float red[256];
  int tid = threadIdx.x;
  float s = 0.f;
  for (int t = tid; t < TT; t += 256) {
    int p = posi[t];
    float denom = fmaxf((float)counts[p] * (float)MM, 1.0f);
    s += rowent[t] / denom;
  }
  red[tid] = s; __syncthreads();
  for (int o = 128; o > 0; o >>= 1) { if (tid < o) red[tid] += red[tid + o]; __syncthreads(); }
  if (tid == 0) out_loss[0] = -red[0] * 0.01f;
}

// ---------------- launcher ----------------
extern "C" void kernel_launch(void* const* d_in, const int* in_sizes, int n_in,
                              void* d_out, int out_size, void* d_ws, size_t ws_size,
                              hipStream_t stream) {
  const int*   inp_word = (const int*)d_in[0];
  const int*   inp_pos  = (const int*)d_in[1];
  const float* inp_mask = (const float*)d_in[2];
  const float* gum      = (const float*)d_in[3];
  const float* wemb     = (const float*)d_in[4];
  const float* pemb     = (const float*)d_in[5];
  const float* Wx_f     = (const float*)d_in[6];
  const float* Wh_f     = (const float*)d_in[7];
  const float* b_f      = (const float*)d_in[8];
  const float* Wx_b     = (const float*)d_in[9];
  const float* Wh_b     = (const float*)d_in[10];
  const float* b_b      = (const float*)d_in[11];
  const float* decW     = (const float*)d_in[12];
  const float* decb     = (const float*)d_in[13];
  const int*   wtbl     = (const int*)d_in[14];
  const float* psrw     = (const float*)d_in[15];

  float* out_word = (float*)d_out;
  float* out_emb  = out_word + TT;
  float* out_mask = out_emb + (size_t)TT * EE;
  float* out_pri  = out_mask + TT;
  float* out_loss = out_pri + TT;

  float* ws = (float*)d_ws;
  float* X      = ws;
  float* GXf    = X + (size_t)TT * DIN;
  float* GXb    = GXf + (size_t)TT * G4;
  float* ctxb   = GXb + (size_t)TT * G4;
  unsigned long long* Hpair = (unsigned long long*)(ctxb + (size_t)TT * MM);
  float* rowent = (float*)(Hpair + 65536);
  int* avoidb   = (int*)(rowent + TT);
  int* counts   = avoidb + TT;
  int* offs     = counts + 16;
  int* idxlist  = offs + 32;
  float* Z    = GXf;   // reuse: GX dead after LSTM
  float* SPT  = Z;     // in-place row rewrite in k_softmax

  k_embed<<<TT, 64, 0, stream>>>(inp_word, inp_pos, wemb, pemb, X);
  k_gemm2<<<dim3(2 * G4 / 128, TT / 128), 256, 0, stream>>>(X, Wx_f, Wx_b, b_f, b_b, GXf, GXb);

  k_initH<<<256, 256, 0, stream>>>(Hpair);
  {
    const int ldsz = 32768;  // max(Wtmp 32KB, Hs+part ~22.7KB)
    hipFuncSetAttribute((const void*)k_lstm7,
                        hipFuncAttributeMaxDynamicSharedMemorySize, ldsz);
    k_lstm7<<<256, 512, ldsz, stream>>>(Wh_f, Wh_b, GXf, GXb, inp_mask, Hpair, ctxb);
  }

  k_zero16<<<1, 64, 0, stream>>>(counts);
  k_count<<<TT / 256, 256, 0, stream>>>(inp_pos, counts);
  k_prefix<<<1, 64, 0, stream>>>(counts, offs);
  k_compact<<<NTAGS, 256, 0, stream>>>(inp_pos, offs, idxlist);
  k_decgemm<<<dim3(MM / 128, TT / 128, NTAGS), 256, 0, stream>>>(ctxb, decW, decb, counts, offs, idxlist, Z);
  k_softmax<<<TT, 256, 0, stream>>>(Z, gum, inp_pos, inp_word, wtbl, SPT, rowent, avoidb,
                                    out_word, out_mask, out_pri);
  k_embgemm<<<dim3(TT / 64, NTAGS), 256, 0, stream>>>(SPT, wtbl, psrw, counts, offs, idxlist,
                                                      avoidb, out_emb);
  k_final<<<1, 256, 0, stream>>>(rowent, inp_pos, counts, out_loss);
}